// Round 9
// baseline (505.813 us; speedup 1.0000x reference)
//
#include <hip/hip_runtime.h>
#include <hip/hip_bf16.h>
#include <math.h>

typedef unsigned short u16;
typedef unsigned int u32;
typedef __bf16 bf16x8 __attribute__((ext_vector_type(8)));
typedef float f32x4 __attribute__((ext_vector_type(4)));
typedef u32 u32x4 __attribute__((ext_vector_type(4)));

__device__ __forceinline__ u16 f2bf(float f) {
  __hip_bfloat16 h = __float2bfloat16(f);
  return *reinterpret_cast<u16*>(&h);
}
__device__ __forceinline__ float bf2f(u16 u) {
  return __uint_as_float(((u32)u) << 16);
}

// async global->LDS, 16B per lane; LDS dest = wave-uniform base + lane*16
#define GLL(gp, lp)                                                     \
  __builtin_amdgcn_global_load_lds(                                     \
      (const __attribute__((address_space(1))) void*)(gp),              \
      (__attribute__((address_space(3))) void*)(lp), 16, 0, 0)

// ---------------------------------------------------------------------------
// Transpose + cast fp32 (R x C) -> bf16 (C x R)
// ---------------------------------------------------------------------------
__global__ __launch_bounds__(256) void transpose_cast(
    const float* __restrict__ in, u16* __restrict__ out, int R, int C) {
  __shared__ float tile[32][33];
  int c0 = blockIdx.x * 32, r0 = blockIdx.y * 32;
  int tx = threadIdx.x & 31, ty = threadIdx.x >> 5;
  for (int i = ty; i < 32; i += 8) {
    int r = r0 + i, c = c0 + tx;
    if (r < R && c < C) tile[i][tx] = in[(size_t)r * C + c];
  }
  __syncthreads();
  for (int i = ty; i < 32; i += 8) {
    int c = c0 + i, r = r0 + tx;
    if (c < C && r < R) out[(size_t)c * R + r] = f2bf(tile[tx][i]);
  }
}

// wq/wk/wv transposes in ONE launch (1024x1024 each, z selects src)
__global__ __launch_bounds__(256) void transpose_cast3(
    const float* __restrict__ in0, const float* __restrict__ in1,
    const float* __restrict__ in2, u16* __restrict__ out) {
  __shared__ float tile[32][33];
  const float* in = (blockIdx.z == 0) ? in0 : (blockIdx.z == 1) ? in1 : in2;
  u16* o = out + (size_t)blockIdx.z * 1024 * 1024;
  int c0 = blockIdx.x * 32, r0 = blockIdx.y * 32;
  int tx = threadIdx.x & 31, ty = threadIdx.x >> 5;
  for (int i = ty; i < 32; i += 8)
    tile[i][tx] = in[(size_t)(r0 + i) * 1024 + c0 + tx];
  __syncthreads();
  for (int i = ty; i < 32; i += 8)
    o[(size_t)(c0 + i) * 1024 + r0 + tx] = f2bf(tile[tx][i]);
}

// pack bq,bk,bv -> 3072-float bias; ALSO zeroes the fattn work-steal counter
__global__ __launch_bounds__(256) void pack3(
    const float* __restrict__ a, const float* __restrict__ b,
    const float* __restrict__ c, float* __restrict__ o, u32* __restrict__ ctr) {
  int t = blockIdx.x * 256 + threadIdx.x;
  if (t == 0) *ctr = 0u;
  if (t < 1024) o[t] = a[t];
  else if (t < 2048) o[t] = b[t - 1024];
  else if (t < 3072) o[t] = c[t - 2048];
}

// ---------------------------------------------------------------------------
// LayerNorm over last dim (1024), fp32 in -> bf16 out. One block per row.
// Optional fused "xadd[i] = x[i] + addb[col]" second output (LN2 seeds d_out
// with b2 so MLP2's split-K can accumulate atomically).
// ---------------------------------------------------------------------------
__global__ __launch_bounds__(256) void ln_kernel(
    const float* x, const float* __restrict__ g,
    const float* __restrict__ bb, u16* __restrict__ out,
    float* xadd, const float* addb) {
  __shared__ float red[8];
  const int row = blockIdx.x;
  const float* xr = x + (size_t)row * 1024;
  f32x4 v = *(const f32x4*)(xr + threadIdx.x * 4);
  float s = v[0] + v[1] + v[2] + v[3];
  #pragma unroll
  for (int off = 32; off > 0; off >>= 1) s += __shfl_xor(s, off, 64);
  if ((threadIdx.x & 63) == 0) red[threadIdx.x >> 6] = s;
  __syncthreads();
  float mu = (red[0] + red[1] + red[2] + red[3]) * (1.0f / 1024.0f);
  f32x4 d;
  d[0] = v[0] - mu; d[1] = v[1] - mu; d[2] = v[2] - mu; d[3] = v[3] - mu;
  float sq = d[0]*d[0] + d[1]*d[1] + d[2]*d[2] + d[3]*d[3];
  #pragma unroll
  for (int off = 32; off > 0; off >>= 1) sq += __shfl_xor(sq, off, 64);
  if ((threadIdx.x & 63) == 0) red[4 + (threadIdx.x >> 6)] = sq;
  __syncthreads();
  float var = (red[4] + red[5] + red[6] + red[7]) * (1.0f / 1024.0f);
  float rstd = rsqrtf(var + 1e-5f);
  int cb = threadIdx.x * 4;
  #pragma unroll
  for (int e = 0; e < 4; ++e)
    out[(size_t)row * 1024 + cb + e] = f2bf(d[e] * rstd * g[cb + e] + bb[cb + e]);
  if (xadd) {
    f32x4 w;
    #pragma unroll
    for (int e = 0; e < 4; ++e) w[e] = v[e] + addb[cb + e];
    *(f32x4*)(xadd + (size_t)row * 1024 + cb) = w;
  }
}

// ---------------------------------------------------------------------------
// Round-17: 256x256 bf16 MFMA GEMM, BK=64, 512 threads = 8 waves (2Mx4N),
// per-wave output 128x64 (acc[8][4]), ported from the guide's verified
// 8-phase template (m194-m201). The 128^2 2-barrier structure plateaued at
// MfmaUtil ~16% across 5 rounds of pipeline variants (re-proving m131-m141);
// this structure is the documented escape (1563 TF @4k, 1.7x).
//  - LDS 128 KB: 2 buffers x (A 256x64 + B 256x64) bf16. 1 block/CU.
//  - XOR swizzle (T2): LDS[row][c8] holds global col-group c8^(row&7).
//    Applied on the GLL SOURCE address (linear dest, rule #21) and on the
//    swizzled ds_read. Kills the 16-way conflict of 128B-stride rows.
//  - 4 quadrant-phases per K-tile: phase q = {ds_read A-frags for 2 m-rows,
//    setprio(1), 16 MFMA, setprio(0), s_barrier}. B-frags (8 x b128) loaded
//    once per K-tile, held in 32 VGPRs.
//  - Prefetch of K-tile t+1 (8 GLL/wave: B-halves in phase 1, A-halves in
//    phase 2) issued AFTER the top barrier; dest = the buffer consumed at
//    t-1, whose last reads retired before that barrier (WAR barrier-proof).
//  - ONE vmcnt(0) per K-tile (top); oldest loads get ~3-4 phases (~500cy)
//    of flight; between drains a wave issues 64 MFMA.
// mode 0: fp32  1: fp32+res  2: bf16 gelu  3: bf16  4: atomic fp32 add
// Split-K via blockIdx.z * Ksl (Ksl == K and gridDim.z == 1 when unsplit).
// ---------------------------------------------------------------------------
__global__ __launch_bounds__(512, 2) void gemm256(
    const u16* __restrict__ A, const u16* __restrict__ Bt,
    const float* __restrict__ bias, const float* __restrict__ res,
    void* __restrict__ outp, int M, int N, int K, int mode, int Ksl) {
  __shared__ u16 As[2 * 256 * 64];   // 64 KB
  __shared__ u16 Bs[2 * 256 * 64];   // 64 KB
  const int tid = threadIdx.x;
  const int wave = tid >> 6, lane = tid & 63;
  const int wm = wave >> 2, wn = wave & 3;
  const int lr = lane & 15, quad = lane >> 4;
  const int m0 = blockIdx.y * 256, n0 = blockIdx.x * 256;
  const int kbeg = blockIdx.z * Ksl;
  const int KT = Ksl >> 6;           // 64-wide K-tiles in this slice

  // staging: chunk g = wave*4+j covers tile-rows g*8..g*8+7 (8 rows x 64 cols
  // = 1 KB = one GLL). lane -> row_off = lane>>3, source col-group swizzled.
  const int srow = lane >> 3;                 // 0..7
  const int scol8 = (lane & 7) ^ srow;        // involution swizzle
  const u16* Aga[4]; const u16* Bga[4];
  #pragma unroll
  for (int j = 0; j < 4; ++j) {
    const int g = wave * 4 + j;
    Aga[j] = A + (size_t)(m0 + g * 8 + srow) * K + kbeg + scol8 * 8;
    Bga[j] = Bt + (size_t)(n0 + g * 8 + srow) * K + kbeg + scol8 * 8;
  }

  f32x4 acc[8][4] = {};

  // prologue: stage K-tile 0 into buffer 0 (8 GLL/wave outstanding)
  #pragma unroll
  for (int j = 0; j < 4; ++j) {
    GLL(Aga[j], As + (wave * 4 + j) * 512);
    GLL(Bga[j], Bs + (wave * 4 + j) * 512);
  }

#define QUAD(q)                                                            \
  {                                                                        \
    bf16x8 af[2][2];                                                       \
    _Pragma("unroll")                                                      \
    for (int mi = 0; mi < 2; ++mi) {                                       \
      const int row = wm * 128 + ((q) * 2 + mi) * 16 + lr;                 \
      _Pragma("unroll")                                                    \
      for (int ks = 0; ks < 2; ++ks) {                                     \
        const int c8 = (ks * 4 + quad) ^ (row & 7);                        \
        af[mi][ks] = *(const bf16x8*)&As[buf + row * 64 + c8 * 8];         \
      }                                                                    \
    }                                                                      \
    __builtin_amdgcn_s_setprio(1);                                         \
    _Pragma("unroll")                                                      \
    for (int mi = 0; mi < 2; ++mi)                                         \
      _Pragma("unroll")                                                    \
      for (int nt = 0; nt < 4; ++nt) {                                     \
        acc[(q) * 2 + mi][nt] = __builtin_amdgcn_mfma_f32_16x16x32_bf16(   \
            af[mi][0], bfr[nt][0], acc[(q) * 2 + mi][nt], 0, 0, 0);        \
        acc[(q) * 2 + mi][nt] = __builtin_amdgcn_mfma_f32_16x16x32_bf16(   \
            af[mi][1], bfr[nt][1], acc[(q) * 2 + mi][nt], 0, 0, 0);        \
      }                                                                    \
    __builtin_amdgcn_s_setprio(0);                                         \
  }

  for (int kt = 0; kt < KT; ++kt) {
    const int buf = (kt & 1) << 14;     // 0 or 16384 elements
    const int pbuf = 16384 - buf;
    const int koff = (kt + 1) * 64;
    // K-tile kt fully landed (all 8 of this wave's prefetch loads)
    asm volatile("s_waitcnt vmcnt(0)" ::: "memory");
    __builtin_amdgcn_s_barrier();       // T_kt visible; pbuf (T_{kt-1}) dead
    __builtin_amdgcn_sched_barrier(0);
    // phase 1: prefetch next B half-tiles; load B frags; quadrant 0
    if (kt + 1 < KT) {
      #pragma unroll
      for (int j = 0; j < 4; ++j)
        GLL(Bga[j] + koff, Bs + pbuf + (wave * 4 + j) * 512);
    }
    bf16x8 bfr[4][2];
    #pragma unroll
    for (int nt = 0; nt < 4; ++nt) {
      const int row = wn * 64 + nt * 16 + lr;
      #pragma unroll
      for (int ks = 0; ks < 2; ++ks) {
        const int c8 = (ks * 4 + quad) ^ (row & 7);
        bfr[nt][ks] = *(const bf16x8*)&Bs[buf + row * 64 + c8 * 8];
      }
    }
    QUAD(0)
    __builtin_amdgcn_sched_barrier(0);
    __builtin_amdgcn_s_barrier();
    // phase 2: prefetch next A half-tiles; quadrant 1
    if (kt + 1 < KT) {
      #pragma unroll
      for (int j = 0; j < 4; ++j)
        GLL(Aga[j] + koff, As + pbuf + (wave * 4 + j) * 512);
    }
    QUAD(1)
    __builtin_amdgcn_sched_barrier(0);
    __builtin_amdgcn_s_barrier();
    // phase 3
    QUAD(2)
    __builtin_amdgcn_sched_barrier(0);
    __builtin_amdgcn_s_barrier();
    // phase 4 (no trailing barrier: next top vmcnt+barrier covers)
    QUAD(3)
  }
#undef QUAD

  // epilogue: per-wave 128x64
  #pragma unroll
  for (int mt = 0; mt < 8; ++mt) {
    #pragma unroll
    for (int nt = 0; nt < 4; ++nt) {
      const int col = n0 + wn * 64 + nt * 16 + lr;
      float bvv = (mode <= 3) ? bias[col] : 0.f;
      #pragma unroll
      for (int rr = 0; rr < 4; ++rr) {
        const int row = m0 + wm * 128 + mt * 16 + quad * 4 + rr;
        const size_t idx = (size_t)row * N + col;
        float v = acc[mt][nt][rr] + bvv;
        if (mode == 0) {
          ((float*)outp)[idx] = v;
        } else if (mode == 1) {
          ((float*)outp)[idx] = v + res[idx];
        } else if (mode == 2) {
          float gl = 0.5f * v * (1.0f + erff(v * 0.70710678118654752f));
          ((u16*)outp)[idx] = f2bf(gl);
        } else if (mode == 3) {
          ((u16*)outp)[idx] = f2bf(v);
        } else {
          __hip_atomic_fetch_add(&((float*)outp)[idx], v,
                                 __ATOMIC_RELAXED, __HIP_MEMORY_SCOPE_AGENT);
        }
      }
    }
  }
}

// ---------------------------------------------------------------------------
// bf16 MFMA GEMM, 128x64 tile (N-skinny), 2-slot counted-vmcnt pipeline
// (3 GLL/step -> vmcnt 3/0; 24 KB LDS). Out-projection (512 blocks).
// ---------------------------------------------------------------------------
__global__ __launch_bounds__(256) void gemm_n64(
    const u16* __restrict__ A, const u16* __restrict__ Bt,
    const float* __restrict__ bias, const float* __restrict__ res,
    void* __restrict__ outp, int M, int N, int K, int mode) {
  __shared__ u16 As[2 * 128 * 32];
  __shared__ u16 Bs[2 * 64 * 32];
  const int tid = threadIdx.x;
  const int m0 = blockIdx.y * 128, n0 = blockIdx.x * 64;
  const int wave = tid >> 6, lane = tid & 63;
  const int wm = (wave >> 1) * 64, wn = (wave & 1) * 32;
  const int lr = lane & 15, quad = lane >> 4;
  const int g0 = wave * 2;
  const int srow = lane >> 2;
  const int scol = (lane & 3) * 8;
  const u16* Ag0 = A + (size_t)(m0 + g0 * 16 + srow) * K + scol;
  const u16* Ag1 = A + (size_t)(m0 + g0 * 16 + 16 + srow) * K + scol;
  const u16* Bg  = Bt + (size_t)(n0 + wave * 16 + srow) * K + scol;
  const int ao0 = g0 * 512, ao1 = (g0 + 1) * 512, bo = wave * 512;

  f32x4 acc[4][2] = {};

  GLL(Ag0, As + ao0); GLL(Ag1, As + ao1); GLL(Bg, Bs + bo);

  for (int k0 = 0; k0 < K; k0 += 32) {
    const int st = (k0 >> 5) & 1;
    const int cba = st * 4096, cbb = st * 2048;
    if (k0 + 32 < K) {
      GLL(Ag0 + k0 + 32, As + (4096 - cba) + ao0);
      GLL(Ag1 + k0 + 32, As + (4096 - cba) + ao1);
      GLL(Bg + k0 + 32, Bs + (2048 - cbb) + bo);
      asm volatile("s_waitcnt vmcnt(3)" ::: "memory");
    } else {
      asm volatile("s_waitcnt vmcnt(0)" ::: "memory");
    }
    __builtin_amdgcn_s_barrier();
    __builtin_amdgcn_sched_barrier(0);
    bf16x8 af[4], bfr[2];
    #pragma unroll
    for (int t = 0; t < 4; ++t)
      af[t] = *(const bf16x8*)&As[cba + (wm + t * 16 + lr) * 32 + quad * 8];
    #pragma unroll
    for (int t = 0; t < 2; ++t)
      bfr[t] = *(const bf16x8*)&Bs[cbb + (wn + t * 16 + lr) * 32 + quad * 8];
    __builtin_amdgcn_s_setprio(1);
    #pragma unroll
    for (int mt = 0; mt < 4; ++mt)
      #pragma unroll
      for (int nt = 0; nt < 2; ++nt)
        acc[mt][nt] = __builtin_amdgcn_mfma_f32_16x16x32_bf16(
            af[mt], bfr[nt], acc[mt][nt], 0, 0, 0);
    __builtin_amdgcn_s_setprio(0);
    __builtin_amdgcn_sched_barrier(0);
    __builtin_amdgcn_s_barrier();
    __builtin_amdgcn_sched_barrier(0);
  }

  #pragma unroll
  for (int mt = 0; mt < 4; ++mt) {
    #pragma unroll
    for (int nt = 0; nt < 2; ++nt) {
      const int col = n0 + wn + nt * 16 + lr;
      const float bvv = bias[col];
      #pragma unroll
      for (int rr = 0; rr < 4; ++rr) {
        const int row = m0 + wm + mt * 16 + quad * 4 + rr;
        const size_t idx = (size_t)row * N + col;
        float v = acc[mt][nt][rr] + bvv;
        if (mode == 0) {
          ((float*)outp)[idx] = v;
        } else if (mode == 1) {
          ((float*)outp)[idx] = v + res[idx];
        } else if (mode == 2) {
          float gl = 0.5f * v * (1.0f + erff(v * 0.70710678118654752f));
          ((u16*)outp)[idx] = f2bf(gl);
        } else {
          ((u16*)outp)[idx] = f2bf(v);
        }
      }
    }
  }
}

// ---------------------------------------------------------------------------
// logf = log_sigmoid(h @ wf + bf), one wave per row. wfT is (16 x 1024) bf16.
// ---------------------------------------------------------------------------
__global__ __launch_bounds__(64) void logf_kernel(
    const u16* __restrict__ h, const u16* __restrict__ wfT,
    const float* __restrict__ bfv, float* __restrict__ c) {
  const int row = blockIdx.x;
  const int lane = threadIdx.x;
  float acc[16];
  #pragma unroll
  for (int n = 0; n < 16; ++n) acc[n] = 0.f;
  for (int t = 0; t < 16; ++t) {
    int kidx = t * 64 + lane;
    float hv = bf2f(h[(size_t)row * 1024 + kidx]);
    #pragma unroll
    for (int n = 0; n < 16; ++n)
      acc[n] += hv * bf2f(wfT[n * 1024 + kidx]);
  }
  float z = 0.f;
  #pragma unroll
  for (int n = 0; n < 16; ++n) {
    float r = acc[n];
    #pragma unroll
    for (int off = 1; off < 64; off <<= 1) r += __shfl_xor(r, off, 64);
    if (lane == n) z = r;
  }
  if (lane < 16) {
    z += bfv[lane];
    float lf = (z >= 0.f) ? -log1pf(expf(-z)) : (z - log1pf(expf(z)));
    c[(size_t)row * 16 + lane] = lf;
  }
}

__global__ __launch_bounds__(64) void cumsum_kernel(float* __restrict__ c, int S) {
  const int b = blockIdx.x >> 4, h = blockIdx.x & 15;
  const int lane = threadIdx.x;
  float carry = 0.f;
  for (int s0 = 0; s0 < S; s0 += 64) {
    float v = c[(size_t)(b * S + s0 + lane) * 16 + h];
    #pragma unroll
    for (int off = 1; off < 64; off <<= 1) {
      float t = __shfl_up(v, off, 64);
      if (lane >= off) v += t;
    }
    v += carry;
    c[(size_t)(b * S + s0 + lane) * 16 + h] = v;
    carry = __shfl(v, 63, 64);
  }
}

// ---------------------------------------------------------------------------
// V^T prep: qkvb V-part (token-major) -> vtg[(b,h,d), s] bf16
// ---------------------------------------------------------------------------
__global__ __launch_bounds__(256) void vtrans(
    const u16* __restrict__ qkvb, u16* __restrict__ vtg) {
  __shared__ u16 t[32][33];
  const int bh = blockIdx.z, b = bh >> 4, h = bh & 15;
  const int s0 = blockIdx.x * 32, d0 = blockIdx.y * 32;
  const int tx = threadIdx.x & 31, ty = threadIdx.x >> 5;
  for (int i = ty; i < 32; i += 8)
    t[i][tx] = qkvb[(size_t)(b * 2048 + s0 + i) * 3072 + 2048 + h * 64 + d0 + tx];
  __syncthreads();
  for (int i = ty; i < 32; i += 8)
    vtg[(size_t)(bh * 64 + d0 + i) * 2048 + s0 + tx] = t[tx][i];
}

// ---------------------------------------------------------------------------
// Per-tile q/k L2-norm maxima for the fattn tile-skip bound.
// ---------------------------------------------------------------------------
__global__ __launch_bounds__(64) void qk_norms(
    const u16* __restrict__ qkvb, float* __restrict__ qkmax) {
  const int tile = blockIdx.x, bh = blockIdx.y, z = blockIdx.z;
  const int b = bh >> 4, h = bh & 15;
  const int tok = tile * 64 + (int)threadIdx.x;
  const u16* p = qkvb + (size_t)(b * 2048 + tok) * 3072 + z * 1024 + h * 64;
  float s = 0.f;
  #pragma unroll
  for (int i = 0; i < 4; ++i) {
    u32x4 w = *(const u32x4*)(p + i * 16);
    u32x4 w2 = *(const u32x4*)(p + i * 16 + 8);
    #pragma unroll
    for (int e = 0; e < 4; ++e) {
      float lo = __uint_as_float(w[e] << 16);
      float hi = __uint_as_float(w[e] & 0xffff0000u);
      float lo2 = __uint_as_float(w2[e] << 16);
      float hi2 = __uint_as_float(w2[e] & 0xffff0000u);
      s += lo * lo + hi * hi + lo2 * lo2 + hi2 * hi2;
    }
  }
  s = sqrtf(s);
  #pragma unroll
  for (int off = 1; off < 64; off <<= 1) s = fmaxf(s, __shfl_xor(s, off, 64));
  if (threadIdx.x == 0) qkmax[z * 1024 + bh * 32 + tile] = s;
}

// ---------------------------------------------------------------------------
// MFMA flash attention with forget-gate decay bias.
//  - ci dropped (row-constant bias cancels in softmax)
//  - DESCENDING k-tile order + Cauchy-Schwarz early-exit (weights < 2^-40)
//  - 1024 blocks (4/CU), K/V/cj register prefetch pipeline
// ---------------------------------------------------------------------------
#define FS 72
#define NITEMS 1024  // 32 q-tiles * 32 bh
#define L2E 1.4426950408889634f

__global__ __launch_bounds__(256) void fattn(
    const u16* __restrict__ qkvb, const u16* __restrict__ vtg,
    const float* __restrict__ c, const float* __restrict__ qkmax,
    u16* __restrict__ ctx, u32* __restrict__ ctr) {
  __shared__ u16 Qs[64 * FS];
  __shared__ u16 Ks[64 * FS];
  __shared__ u16 Vt[64 * FS];
  __shared__ u16 Ps[64 * FS];
  __shared__ float cjs[64];
  __shared__ float wmn[4];
  __shared__ u32 sh_item;
  const int S = 2048;
  const int tid = threadIdx.x, wave = tid >> 6, lane = tid & 63;
  const int lr = lane & 15, quad = lane >> 4;
  const int w16 = wave * 16;
  const int sr = tid >> 2, scc = (tid & 3) * 16;  // staging row/col

  for (;;) {
    if (tid == 0) sh_item = atomicAdd(ctr, 1u);
    __syncthreads();  // publish item (prev item's LDS reads already fenced)
    const u32 item = sh_item;
    if (item >= NITEMS) return;
    const int qt = 31 - (int)(item >> 5);       // descending work
    const int bh = (int)(item & 31), b = bh >> 4, h = bh & 15;
    const int i0 = qt * 64;

    {  // stage Q tile (64x64 bf16)
      const u16* src = qkvb + (size_t)(b * S + i0 + sr) * 3072 + h * 64 + scc;
      *(u32x4*)&Qs[sr * FS + scc] = *(const u32x4*)src;
      *(u32x4*)&Qs[sr * FS + scc + 8] = *(const u32x4*)(src + 8);
    }
    // prefetch K/V/cj for the DIAGONAL tile (jt = qt) into registers
    u32x4 kr0, kr1, vr0, vr1;
    float cjr = 0.f;
    {
      const u16* ks = qkvb + (size_t)(b * S + i0 + sr) * 3072 + 1024 + h * 64 + scc;
      kr0 = *(const u32x4*)ks;
      kr1 = *(const u32x4*)(ks + 8);
      const u16* vs = vtg + (size_t)(bh * 64 + sr) * 2048 + i0 + scc;
      vr0 = *(const u32x4*)vs;
      vr1 = *(const u32x4*)(vs + 8);
      if (tid < 64) cjr = c[(size_t)(b * S + i0 + tid) * 16 + h];
    }
    // Cauchy-Schwarz score bound scale
    float bscale;
    {
      float qm = qkmax[bh * 32 + qt];
      float km = 0.f;
      for (int t = 0; t <= qt; ++t) km = fmaxf(km, qkmax[1024 + bh * 32 + t]);
      bscale = qm * km * (0.125f * L2E);
    }
    float m_[4], l_[4], alpha[4];
    f32x4 o_[4];
    #pragma unroll
    for (int r = 0; r < 4; ++r) {
      m_[r] = -INFINITY;
      l_[r] = 0.f;
    }
    #pragma unroll
    for (int dt = 0; dt < 4; ++dt) o_[dt] = (f32x4){0.f, 0.f, 0.f, 0.f};

    __syncthreads();  // Q visible
    const bf16x8 aq0 = *(const bf16x8*)&Qs[(w16 + lr) * FS + quad * 8];
    const bf16x8 aq1 = *(const bf16x8*)&Qs[(w16 + lr) * FS + 32 + quad * 8];

    for (int jt = qt; jt >= 0; --jt) {
      const int j0 = jt * 64;
      // write prefetched tile jt to LDS (prev iter's reads fenced by barrier)
      *(u32x4*)&Ks[sr * FS + scc] = kr0;
      *(u32x4*)&Ks[sr * FS + scc + 8] = kr1;
      *(u32x4*)&Vt[sr * FS + scc] = vr0;
      *(u32x4*)&Vt[sr * FS + scc + 8] = vr1;
      if (tid < 64) cjs[tid] = cjr * L2E;
      // issue prefetch for tile jt-1
      if (jt > 0) {
        const int j1 = j0 - 64;
        const u16* ks = qkvb + (size_t)(b * S + j1 + sr) * 3072 + 1024 + h * 64 + scc;
        kr0 = *(const u32x4*)ks;
        kr1 = *(const u32x4*)(ks + 8);
        const u16* vs = vtg + (size_t)(bh * 64 + sr) * 2048 + j1 + scc;
        vr0 = *(const u32x4*)vs;
        vr1 = *(const u32x4*)(vs + 8);
        if (tid < 64) cjr = c[(size_t)(b * S + j1 + tid) * 16 + h];
      }
      __syncthreads();  // K/V visible

      f32x4 sc[4];
      #pragma unroll
      for (int nt = 0; nt < 4; ++nt) {
        bf16x8 bk0 = *(const bf16x8*)&Ks[(nt * 16 + lr) * FS + quad * 8];
        bf16x8 bk1 = *(const bf16x8*)&Ks[(nt * 16 + lr) * FS + 32 + quad * 8];
        f32x4 z = {0.f, 0.f, 0.f, 0.f};
        z = __builtin_amdgcn_mfma_f32_16x16x32_bf16(aq0, bk0, z, 0, 0, 0);
        z = __builtin_amdgcn_mfma_f32_16x16x32_bf16(aq1, bk1, z, 0, 0, 0);
        sc[nt] = z;
      }
      const bool diag = (jt == qt);
      #pragma unroll
      for (int r = 0; r < 4; ++r) {
        const int i = i0 + w16 + quad * 4 + r;
        float lg[4], mrow = -INFINITY;
        #pragma unroll
        for (int nt = 0; nt < 4; ++nt) {
          const int j = j0 + nt * 16 + lr;
          float v = sc[nt][r] * (0.125f * L2E) - cjs[nt * 16 + lr];
          if (diag && (j > i)) v = -INFINITY;
          lg[nt] = v;
          mrow = fmaxf(mrow, v);
        }
        #pragma unroll
        for (int off = 1; off < 16; off <<= 1)
          mrow = fmaxf(mrow, __shfl_xor(mrow, off, 64));
        const float mn = fmaxf(m_[r], mrow);
        alpha[r] = __builtin_exp2f(m_[r] - mn);
        m_[r] = mn;
        float rs = 0.f;
        #pragma unroll
        for (int nt = 0; nt < 4; ++nt) {
          const float p = __builtin_exp2f(lg[nt] - mn);
          Ps[(w16 + quad * 4 + r) * FS + nt * 16 + lr] = f2bf(p);
          rs += p;
        }
        l_[r] = l_[r] * alpha[r] + rs;  // per-lane partial (reduced at end)
      }
      // make this wave's P writes visible to its own b128 reads
      asm volatile("s_waitcnt lgkmcnt(0)" ::: "memory");
      #pragma unroll
      for (int dt = 0; dt < 4; ++dt)
        #pragma unroll
        for (int r = 0; r < 4; ++r) o_[dt][r] *= alpha[r];
      bf16x8 ap0 = *(const bf16x8*)&Ps[(w16 + lr) * FS + quad * 8];
      bf16x8 ap1 = *(const bf16x8*)&Ps[(w16 + lr) * FS + 32 + quad * 8];
      #pragma unroll
      for (int dt = 0; dt < 4; ++dt) {
        bf16x8 bv0 = *(const bf16x8*)&Vt[(dt * 16 + lr) * FS + quad * 8];
        bf16x8 bv1 = *(const bf16x8*)&Vt[(dt * 16 + lr) * FS + 32 + quad * 8];
        o_[dt] = __builtin_amdgcn_mfma_f32_16x16x32_bf16(ap0, bv0, o_[dt], 0, 0, 0);
        o_[dt] = __builtin_amdgcn_mfma_f32_16x16x32_bf16(ap1, bv1, o_[dt], 0, 0, 0);
      }
      // publish this wave's running-max minimum for the skip decision
      {
        float wmin = fminf(fminf(m_[0], m_[1]), fminf(m_[2], m_[3]));
        wmin = fminf(wmin, __shfl_xor(wmin, 16, 64));
        wmin = fminf(wmin, __shfl_xor(wmin, 32, 64));
        if (lane == 0) wmn[wave] = wmin;
      }
      __syncthreads();  // all reads of Ks/Vt done before next iter's writes
      if (jt > 0) {
        const float bmin = fminf(fminf(wmn[0], wmn[1]), fminf(wmn[2], wmn[3]));
        const float cend = c[(size_t)(b * S + j0 - 1) * 16 + h];
        if (bscale - cend * L2E < bmin - 40.f) break;
      }
    }
    #pragma unroll
    for (int r = 0; r < 4; ++r) {
      float lt = l_[r];
      #pragma unroll
      for (int off = 1; off < 16; off <<= 1) lt += __shfl_xor(lt, off, 64);
      const float inv = 1.0f / lt;
      const size_t base = (size_t)(b * S + i0 + w16 + quad * 4 + r) * 1024 + h * 64;
      #pragma unroll
      for (int dt = 0; dt < 4; ++dt)
        ctx[base + dt * 16 + lr] = f2bf(o_[dt][r] * inv);
    }
  }
}

// ---------------------------------------------------------------------------
extern "C" void kernel_launch(void* const* d_in, const int* in_sizes, int n_in,
                              void* d_out, int out_size, void* d_ws, size_t ws_size,
                              hipStream_t stream) {
  const float* x    = (const float*)d_in[0];
  const float* ln1g = (const float*)d_in[1];
  const float* ln1b = (const float*)d_in[2];
  const float* wq   = (const float*)d_in[3];
  const float* bq   = (const float*)d_in[4];
  const float* wk   = (const float*)d_in[5];
  const float* bk   = (const float*)d_in[6];
  const float* wv   = (const float*)d_in[7];
  const float* bv   = (const float*)d_in[8];
  const float* wo   = (const float*)d_in[9];
  const float* bo   = (const float*)d_in[10];
  const float* wf   = (const float*)d_in[11];
  const float* bfv  = (const float*)d_in[12];
  const float* ln2g = (const float*)d_in[13];
  const float* ln2b = (const float*)d_in[14];
  const float* w1   = (const float*)d_in[15];
  const float* b1   = (const float*)d_in[16];
  const float* w2   = (const float*)d_in[17];
  const float* b2   = (const float*)d_in[18];
  float* out = (float*)d_out;

  char* ws = (char*)d_ws;
  const size_t MB = 1024 * 1024;
  u16*   wqkvT = (u16*)(ws + 0 * MB);        // 3072x1024 bf16 (6 MB)
  u16*   woT   = (u16*)(ws + 6 * MB);        // 1024x1024 bf16
  u16*   w1T   = (u16*)(ws + 8 * MB);        // 4096x1024 bf16
  u16*   w2T   = (u16*)(ws + 16 * MB);       // 1024x4096 bf16
  u16*   wfT   = (u16*)(ws + 24 * MB);       // 16x1024 bf16
  float* bqkv  = (float*)(ws + 24 * MB + 65536);  // 3072 fp32
  u32*   fctr  = (u32*)(ws + 24 * MB + 131072);   // work-steal counter
  u16*   hbuf  = (u16*)(ws + 25 * MB);       // 4096x1024 bf16
  u16*   ctx   = (u16*)(ws + 33 * MB);       // 4096x1024 bf16
  u16*   qkvb  = (u16*)(ws + 41 * MB);       // 4096x3072 bf16 (24 MB)
  u16*   vtg   = (u16*)(ws + 65 * MB);       // (32*64)x2048 bf16 (8 MB)
  float* cb    = (float*)(ws + 73 * MB);     // 4096x16 fp32 (256 KB)
  float* qkmax = (float*)(ws + 73 * MB + 262144);  // 2x32x32 fp32 (8 KB)
  u16*   act1  = (u16*)(ws + 74 * MB);       // 4096x4096 bf16 (32 MB)

  dim3 blk(256);
  // weight prep (pack3 also zeroes the fattn work-steal counter, on-stream)
  transpose_cast3<<<dim3(32, 32, 3), blk, 0, stream>>>(wq, wk, wv, wqkvT);
  transpose_cast<<<dim3(32, 32), blk, 0, stream>>>(wo, woT, 1024, 1024);
  transpose_cast<<<dim3(128, 32), blk, 0, stream>>>(w1, w1T, 1024, 4096);
  transpose_cast<<<dim3(32, 128), blk, 0, stream>>>(w2, w2T, 4096, 1024);
  transpose_cast<<<dim3(1, 32), blk, 0, stream>>>(wf, wfT, 1024, 16);
  pack3<<<12, blk, 0, stream>>>(bq, bk, bv, bqkv, fctr);
  // LN1
  ln_kernel<<<4096, blk, 0, stream>>>(x, ln1g, ln1b, hbuf, nullptr, nullptr);
  // fused QKV projection -> bf16 (4096 x 3072): 256^2 tiles, 192 blocks
  gemm256<<<dim3(12, 16), dim3(512), 0, stream>>>(
      hbuf, wqkvT, bqkv, nullptr, qkvb, 4096, 3072, 1024, 3, 1024);
  // forget gate
  logf_kernel<<<4096, dim3(64), 0, stream>>>(hbuf, wfT, bfv, cb);
  cumsum_kernel<<<32, dim3(64), 0, stream>>>(cb, 2048);
  // V^T prep + per-tile q/k norm maxima + attention (work-stealing)
  vtrans<<<dim3(64, 2, 32), blk, 0, stream>>>(qkvb, vtg);
  qk_norms<<<dim3(32, 32, 2), dim3(64), 0, stream>>>(qkvb, qkmax);
  fattn<<<dim3(1024), blk, 0, stream>>>(qkvb, vtg, cb, qkmax, ctx, fctr);
  // out projection + residual -> d_out
  gemm_n64<<<dim3(16, 32), blk, 0, stream>>>(ctx, woT, bo, x, out,
                                             4096, 1024, 1024, 1);
  // LN2 (fused: also seeds out += b2 for MLP2's atomic split-K accumulate)
  ln_kernel<<<4096, blk, 0, stream>>>(out, ln2g, ln2b, hbuf, out, b2);
  // MLP1: 256^2 tiles, 256 blocks = 1/CU exact
  gemm256<<<dim3(16, 16), dim3(512), 0, stream>>>(
      hbuf, w1T, b1, nullptr, act1, 4096, 4096, 1024, 2, 1024);
  // MLP2: 256^2 split-K x4 (grid z), atomic accumulate into pre-seeded out
  gemm256<<<dim3(4, 16, 4), dim3(512), 0, stream>>>(
      act1, w2T, nullptr, nullptr, out, 4096, 1024, 4096, 4, 1024);
}

// Round 11
// 458.706 us; speedup vs baseline: 1.1027x; 1.1027x over previous
//
#include <hip/hip_runtime.h>
#include <hip/hip_bf16.h>
#include <math.h>

typedef unsigned short u16;
typedef unsigned int u32;
typedef __bf16 bf16x8 __attribute__((ext_vector_type(8)));
typedef float f32x4 __attribute__((ext_vector_type(4)));
typedef u32 u32x4 __attribute__((ext_vector_type(4)));

__device__ __forceinline__ u16 f2bf(float f) {
  __hip_bfloat16 h = __float2bfloat16(f);
  return *reinterpret_cast<u16*>(&h);
}
__device__ __forceinline__ float bf2f(u16 u) {
  return __uint_as_float(((u32)u) << 16);
}

// async global->LDS, 16B per lane; LDS dest = wave-uniform base + lane*16
#define GLL(gp, lp)                                                     \
  __builtin_amdgcn_global_load_lds(                                     \
      (const __attribute__((address_space(1))) void*)(gp),              \
      (__attribute__((address_space(3))) void*)(lp), 16, 0, 0)

// ---------------------------------------------------------------------------
// Transpose + cast fp32 (R x C) -> bf16 (C x R)
// ---------------------------------------------------------------------------
__global__ __launch_bounds__(256) void transpose_cast(
    const float* __restrict__ in, u16* __restrict__ out, int R, int C) {
  __shared__ float tile[32][33];
  int c0 = blockIdx.x * 32, r0 = blockIdx.y * 32;
  int tx = threadIdx.x & 31, ty = threadIdx.x >> 5;
  for (int i = ty; i < 32; i += 8) {
    int r = r0 + i, c = c0 + tx;
    if (r < R && c < C) tile[i][tx] = in[(size_t)r * C + c];
  }
  __syncthreads();
  for (int i = ty; i < 32; i += 8) {
    int c = c0 + i, r = r0 + tx;
    if (c < C && r < R) out[(size_t)c * R + r] = f2bf(tile[tx][i]);
  }
}

// wq/wk/wv/wo transposes in ONE launch (1024x1024 each, z selects)
__global__ __launch_bounds__(256) void transpose_cast4(
    const float* __restrict__ in0, const float* __restrict__ in1,
    const float* __restrict__ in2, const float* __restrict__ in3,
    u16* __restrict__ out012, u16* __restrict__ out3) {
  __shared__ float tile[32][33];
  const int z = blockIdx.z;
  const float* in = (z == 0) ? in0 : (z == 1) ? in1 : (z == 2) ? in2 : in3;
  u16* o = (z < 3) ? (out012 + (size_t)z * 1024 * 1024) : out3;
  int c0 = blockIdx.x * 32, r0 = blockIdx.y * 32;
  int tx = threadIdx.x & 31, ty = threadIdx.x >> 5;
  for (int i = ty; i < 32; i += 8)
    tile[i][tx] = in[(size_t)(r0 + i) * 1024 + c0 + tx];
  __syncthreads();
  for (int i = ty; i < 32; i += 8)
    o[(size_t)(c0 + i) * 1024 + r0 + tx] = f2bf(tile[tx][i]);
}

// pack bq,bk,bv -> 3072-float bias; ALSO zeroes the fattn work-steal counter
__global__ __launch_bounds__(256) void pack3(
    const float* __restrict__ a, const float* __restrict__ b,
    const float* __restrict__ c, float* __restrict__ o, u32* __restrict__ ctr) {
  int t = blockIdx.x * 256 + threadIdx.x;
  if (t == 0) *ctr = 0u;
  if (t < 1024) o[t] = a[t];
  else if (t < 2048) o[t] = b[t - 1024];
  else if (t < 3072) o[t] = c[t - 2048];
}

// ---------------------------------------------------------------------------
// LayerNorm over last dim (1024), fp32 in -> bf16 out. One block per row.
// Optional fused "xadd[i] = x[i] + addb[col]" second output (LN2 seeds d_out
// with b2 so MLP2's split-K can accumulate atomically).
// ---------------------------------------------------------------------------
__global__ __launch_bounds__(256) void ln_kernel(
    const float* x, const float* __restrict__ g,
    const float* __restrict__ bb, u16* __restrict__ out,
    float* xadd, const float* addb) {
  __shared__ float red[8];
  const int row = blockIdx.x;
  const float* xr = x + (size_t)row * 1024;
  f32x4 v = *(const f32x4*)(xr + threadIdx.x * 4);
  float s = v[0] + v[1] + v[2] + v[3];
  #pragma unroll
  for (int off = 32; off > 0; off >>= 1) s += __shfl_xor(s, off, 64);
  if ((threadIdx.x & 63) == 0) red[threadIdx.x >> 6] = s;
  __syncthreads();
  float mu = (red[0] + red[1] + red[2] + red[3]) * (1.0f / 1024.0f);
  f32x4 d;
  d[0] = v[0] - mu; d[1] = v[1] - mu; d[2] = v[2] - mu; d[3] = v[3] - mu;
  float sq = d[0]*d[0] + d[1]*d[1] + d[2]*d[2] + d[3]*d[3];
  #pragma unroll
  for (int off = 32; off > 0; off >>= 1) sq += __shfl_xor(sq, off, 64);
  if ((threadIdx.x & 63) == 0) red[4 + (threadIdx.x >> 6)] = sq;
  __syncthreads();
  float var = (red[4] + red[5] + red[6] + red[7]) * (1.0f / 1024.0f);
  float rstd = rsqrtf(var + 1e-5f);
  int cb = threadIdx.x * 4;
  #pragma unroll
  for (int e = 0; e < 4; ++e)
    out[(size_t)row * 1024 + cb + e] = f2bf(d[e] * rstd * g[cb + e] + bb[cb + e]);
  if (xadd) {
    f32x4 w;
    #pragma unroll
    for (int e = 0; e < 4; ++e) w[e] = v[e] + addb[cb + e];
    *(f32x4*)(xadd + (size_t)row * 1024 + cb) = w;
  }
}

// ---------------------------------------------------------------------------
// bf16 MFMA GEMM, 128x128 tile, BK=32, 4 waves 2x2, acc[4][4] of 16x16x32.
// Round-19 = the round-14/465.6µs 3-buffer structure (best measured) plus
// CORRECTED T2 XOR-swizzle. r6 counters: 4.19M LDS bank-conflict cycles per
// dispatch on the critical path (lgkmcnt(0)+BAR_B between ds_read and MFMA).
// Layout math: [128][32] bf16 rows are 64B, so a 128B bank stripe holds TWO
// rows; slot(row,cg) = (row&1)*4 + cg. Bijection over 8 consecutive rows
// needs cg ^= (row>>1)&3 (cg ^= row&3 leaves rows 0/4 colliding). Residual
// aliasing: lanes lr/lr+8 share banks = 2-way = free (m136).
// Both-sides involution (rule #21): GLL dest stays LINEAR; SOURCE col-group
// = (lane&3) ^ ((lane>>3)&3)  [since r = lane>>2, (r>>1)&3 = (lane>>3)&3;
// 16-aligned row bases drop out]; read col-offset = (quad ^ ((lr>>1)&3))*8.
// Pipeline (unchanged): GLL(t+2 -> slot); vmcnt(8); BAR_A; ds_read;
// lgkmcnt(0); BAR_B; setprio MFMA. 48 KB LDS -> 3 blocks/CU.
// mode 0: fp32 out   1: fp32 + res   2: bf16 gelu   3: bf16
// ---------------------------------------------------------------------------
__global__ __launch_bounds__(256) void gemm_bt(
    const u16* __restrict__ A, const u16* __restrict__ Bt,
    const float* __restrict__ bias, const float* __restrict__ res,
    void* __restrict__ outp, int M, int N, int K, int mode) {
  __shared__ u16 As[3 * 128 * 32];
  __shared__ u16 Bs[3 * 128 * 32];
  const int tid = threadIdx.x;
  const int m0 = blockIdx.y * 128, n0 = blockIdx.x * 128;
  const int wave = tid >> 6, lane = tid & 63;
  const int wm = (wave >> 1) * 64, wn = (wave & 1) * 64;
  const int lr = lane & 15, quad = lane >> 4;
  const int g0 = wave * 2;
  const int srow0 = g0 * 16 + (lane >> 2);
  const int scol = ((lane & 3) ^ ((lane >> 3) & 3)) * 8;   // swizzled source
  const u16* Ag0 = A + (size_t)(m0 + srow0) * K + scol;
  const u16* Ag1 = A + (size_t)(m0 + srow0 + 16) * K + scol;
  const u16* Bg0 = Bt + (size_t)(n0 + srow0) * K + scol;
  const u16* Bg1 = Bt + (size_t)(n0 + srow0 + 16) * K + scol;
  const int ao0 = g0 * 512, ao1 = (g0 + 1) * 512;
  const int rsw = (quad ^ ((lr >> 1) & 3)) * 8;            // swizzled read

  f32x4 acc[4][4] = {};

  // prologue: stage steps 0,1 into slots 0,1
  GLL(Ag0, As + ao0); GLL(Ag1, As + ao1);
  GLL(Bg0, Bs + ao0); GLL(Bg1, Bs + ao1);
  if (K > 32) {
    GLL(Ag0 + 32, As + 4096 + ao0); GLL(Ag1 + 32, As + 4096 + ao1);
    GLL(Bg0 + 32, Bs + 4096 + ao0); GLL(Bg1 + 32, Bs + 4096 + ao1);
  }

  int cur = 0;
  for (int k0 = 0; k0 < K; k0 += 32) {
    const int cb = cur * 4096;
    if (k0 + 64 < K) {
      int ns = cur + 2; if (ns >= 3) ns -= 3;
      const int pb = ns * 4096;
      GLL(Ag0 + k0 + 64, As + pb + ao0);
      GLL(Ag1 + k0 + 64, As + pb + ao1);
      GLL(Bg0 + k0 + 64, Bs + pb + ao0);
      GLL(Bg1 + k0 + 64, Bs + pb + ao1);
      asm volatile("s_waitcnt vmcnt(8)" ::: "memory");
    } else if (k0 + 32 < K) {
      asm volatile("s_waitcnt vmcnt(4)" ::: "memory");
    } else {
      asm volatile("s_waitcnt vmcnt(0)" ::: "memory");
    }
    __builtin_amdgcn_s_barrier();        // BAR_A: slot cur fully staged
    __builtin_amdgcn_sched_barrier(0);
    bf16x8 af[4], bfr[4];
    #pragma unroll
    for (int t = 0; t < 4; ++t) {
      af[t]  = *(const bf16x8*)&As[cb + (wm + t * 16 + lr) * 32 + rsw];
      bfr[t] = *(const bf16x8*)&Bs[cb + (wn + t * 16 + lr) * 32 + rsw];
    }
    asm volatile("s_waitcnt lgkmcnt(0)" ::: "memory");
    __builtin_amdgcn_sched_barrier(0);
    __builtin_amdgcn_s_barrier();        // BAR_B: all reads of slot cur retired
    __builtin_amdgcn_s_setprio(1);
    #pragma unroll
    for (int mt = 0; mt < 4; ++mt)
      #pragma unroll
      for (int nt = 0; nt < 4; ++nt)
        acc[mt][nt] = __builtin_amdgcn_mfma_f32_16x16x32_bf16(
            af[mt], bfr[nt], acc[mt][nt], 0, 0, 0);
    __builtin_amdgcn_s_setprio(0);
    cur += 1; if (cur >= 3) cur = 0;
  }

  #pragma unroll
  for (int mt = 0; mt < 4; ++mt) {
    #pragma unroll
    for (int nt = 0; nt < 4; ++nt) {
      const int col = n0 + wn + nt * 16 + lr;
      const float bvv = bias[col];
      #pragma unroll
      for (int rr = 0; rr < 4; ++rr) {
        const int row = m0 + wm + mt * 16 + quad * 4 + rr;
        const size_t idx = (size_t)row * N + col;
        float v = acc[mt][nt][rr] + bvv;
        if (mode == 0) {
          ((float*)outp)[idx] = v;
        } else if (mode == 1) {
          ((float*)outp)[idx] = v + res[idx];
        } else if (mode == 2) {
          float gl = 0.5f * v * (1.0f + erff(v * 0.70710678118654752f));
          ((u16*)outp)[idx] = f2bf(gl);
        } else {
          ((u16*)outp)[idx] = f2bf(v);
        }
      }
    }
  }
}

// ---------------------------------------------------------------------------
// Split-K 128x128 tile for MLP2 (N=1024, K=4096). r6 structure + corrected
// swizzle. Split-K x2 (512 blocks), atomic fp32 accumulate into outp
// (pre-seeded with res+b2 by the fused LN2 pass).
// ---------------------------------------------------------------------------
__global__ __launch_bounds__(256) void gemm_bt_sk(
    const u16* __restrict__ A, const u16* __restrict__ Bt,
    float* __restrict__ outp, int M, int N, int Ktot, int Kslice) {
  __shared__ u16 As[3 * 128 * 32];
  __shared__ u16 Bs[3 * 128 * 32];
  const int tid = threadIdx.x;
  const int m0 = blockIdx.y * 128, n0 = blockIdx.x * 128;
  const int kbeg = blockIdx.z * Kslice;
  int kend = kbeg + Kslice; if (kend > Ktot) kend = Ktot;
  const int wave = tid >> 6, lane = tid & 63;
  const int wm = (wave >> 1) * 64, wn = (wave & 1) * 64;
  const int lr = lane & 15, quad = lane >> 4;
  const int g0 = wave * 2;
  const int srow0 = g0 * 16 + (lane >> 2);
  const int scol = ((lane & 3) ^ ((lane >> 3) & 3)) * 8;
  const u16* Ag0 = A + (size_t)(m0 + srow0) * Ktot + scol;
  const u16* Ag1 = A + (size_t)(m0 + srow0 + 16) * Ktot + scol;
  const u16* Bg0 = Bt + (size_t)(n0 + srow0) * Ktot + scol;
  const u16* Bg1 = Bt + (size_t)(n0 + srow0 + 16) * Ktot + scol;
  const int ao0 = g0 * 512, ao1 = (g0 + 1) * 512;
  const int rsw = (quad ^ ((lr >> 1) & 3)) * 8;

  f32x4 acc[4][4] = {};

  GLL(Ag0 + kbeg, As + ao0); GLL(Ag1 + kbeg, As + ao1);
  GLL(Bg0 + kbeg, Bs + ao0); GLL(Bg1 + kbeg, Bs + ao1);
  if (kbeg + 32 < kend) {
    GLL(Ag0 + kbeg + 32, As + 4096 + ao0); GLL(Ag1 + kbeg + 32, As + 4096 + ao1);
    GLL(Bg0 + kbeg + 32, Bs + 4096 + ao0); GLL(Bg1 + kbeg + 32, Bs + 4096 + ao1);
  }

  int cur = 0;
  for (int k0 = kbeg; k0 < kend; k0 += 32) {
    const int cb = cur * 4096;
    if (k0 + 64 < kend) {
      int ns = cur + 2; if (ns >= 3) ns -= 3;
      const int pb = ns * 4096;
      GLL(Ag0 + k0 + 64, As + pb + ao0);
      GLL(Ag1 + k0 + 64, As + pb + ao1);
      GLL(Bg0 + k0 + 64, Bs + pb + ao0);
      GLL(Bg1 + k0 + 64, Bs + pb + ao1);
      asm volatile("s_waitcnt vmcnt(8)" ::: "memory");
    } else if (k0 + 32 < kend) {
      asm volatile("s_waitcnt vmcnt(4)" ::: "memory");
    } else {
      asm volatile("s_waitcnt vmcnt(0)" ::: "memory");
    }
    __builtin_amdgcn_s_barrier();
    __builtin_amdgcn_sched_barrier(0);
    bf16x8 af[4], bfr[4];
    #pragma unroll
    for (int t = 0; t < 4; ++t) {
      af[t]  = *(const bf16x8*)&As[cb + (wm + t * 16 + lr) * 32 + rsw];
      bfr[t] = *(const bf16x8*)&Bs[cb + (wn + t * 16 + lr) * 32 + rsw];
    }
    asm volatile("s_waitcnt lgkmcnt(0)" ::: "memory");
    __builtin_amdgcn_sched_barrier(0);
    __builtin_amdgcn_s_barrier();
    __builtin_amdgcn_s_setprio(1);
    #pragma unroll
    for (int mt = 0; mt < 4; ++mt)
      #pragma unroll
      for (int nt = 0; nt < 4; ++nt)
        acc[mt][nt] = __builtin_amdgcn_mfma_f32_16x16x32_bf16(
            af[mt], bfr[nt], acc[mt][nt], 0, 0, 0);
    __builtin_amdgcn_s_setprio(0);
    cur += 1; if (cur >= 3) cur = 0;
  }

  #pragma unroll
  for (int mt = 0; mt < 4; ++mt) {
    #pragma unroll
    for (int nt = 0; nt < 4; ++nt) {
      const int col = n0 + wn + nt * 16 + lr;
      #pragma unroll
      for (int rr = 0; rr < 4; ++rr) {
        const int row = m0 + wm + mt * 16 + quad * 4 + rr;
        __hip_atomic_fetch_add(&outp[(size_t)row * N + col], acc[mt][nt][rr],
                               __ATOMIC_RELAXED, __HIP_MEMORY_SCOPE_AGENT);
      }
    }
  }
}

// ---------------------------------------------------------------------------
// bf16 MFMA GEMM, 128x64 tile (N-skinny), r6 3-buffer structure + corrected
// swizzle (3 GLL/step -> vmcnt 6/3/0; 36 KB LDS -> 4 blocks/CU). Out-proj.
// ---------------------------------------------------------------------------
__global__ __launch_bounds__(256) void gemm_n64(
    const u16* __restrict__ A, const u16* __restrict__ Bt,
    const float* __restrict__ bias, const float* __restrict__ res,
    void* __restrict__ outp, int M, int N, int K, int mode) {
  __shared__ u16 As[3 * 128 * 32];
  __shared__ u16 Bs[3 * 64 * 32];
  const int tid = threadIdx.x;
  const int m0 = blockIdx.y * 128, n0 = blockIdx.x * 64;
  const int wave = tid >> 6, lane = tid & 63;
  const int wm = (wave >> 1) * 64, wn = (wave & 1) * 32;
  const int lr = lane & 15, quad = lane >> 4;
  const int g0 = wave * 2;
  const int srow = lane >> 2;
  const int scol = ((lane & 3) ^ ((lane >> 3) & 3)) * 8;
  const u16* Ag0 = A + (size_t)(m0 + g0 * 16 + srow) * K + scol;
  const u16* Ag1 = A + (size_t)(m0 + g0 * 16 + 16 + srow) * K + scol;
  const u16* Bg  = Bt + (size_t)(n0 + wave * 16 + srow) * K + scol;
  const int ao0 = g0 * 512, ao1 = (g0 + 1) * 512, bo = wave * 512;
  const int rsw = (quad ^ ((lr >> 1) & 3)) * 8;

  f32x4 acc[4][2] = {};

  GLL(Ag0, As + ao0); GLL(Ag1, As + ao1); GLL(Bg, Bs + bo);
  if (K > 32) {
    GLL(Ag0 + 32, As + 4096 + ao0); GLL(Ag1 + 32, As + 4096 + ao1);
    GLL(Bg + 32, Bs + 2048 + bo);
  }

  int cur = 0;
  for (int k0 = 0; k0 < K; k0 += 32) {
    const int cba = cur * 4096, cbb = cur * 2048;
    if (k0 + 64 < K) {
      int ns = cur + 2; if (ns >= 3) ns -= 3;
      GLL(Ag0 + k0 + 64, As + ns * 4096 + ao0);
      GLL(Ag1 + k0 + 64, As + ns * 4096 + ao1);
      GLL(Bg + k0 + 64, Bs + ns * 2048 + bo);
      asm volatile("s_waitcnt vmcnt(6)" ::: "memory");
    } else if (k0 + 32 < K) {
      asm volatile("s_waitcnt vmcnt(3)" ::: "memory");
    } else {
      asm volatile("s_waitcnt vmcnt(0)" ::: "memory");
    }
    __builtin_amdgcn_s_barrier();
    __builtin_amdgcn_sched_barrier(0);
    bf16x8 af[4], bfr[2];
    #pragma unroll
    for (int t = 0; t < 4; ++t)
      af[t] = *(const bf16x8*)&As[cba + (wm + t * 16 + lr) * 32 + rsw];
    #pragma unroll
    for (int t = 0; t < 2; ++t)
      bfr[t] = *(const bf16x8*)&Bs[cbb + (wn + t * 16 + lr) * 32 + rsw];
    asm volatile("s_waitcnt lgkmcnt(0)" ::: "memory");
    __builtin_amdgcn_sched_barrier(0);
    __builtin_amdgcn_s_barrier();
    __builtin_amdgcn_s_setprio(1);
    #pragma unroll
    for (int mt = 0; mt < 4; ++mt)
      #pragma unroll
      for (int nt = 0; nt < 2; ++nt)
        acc[mt][nt] = __builtin_amdgcn_mfma_f32_16x16x32_bf16(
            af[mt], bfr[nt], acc[mt][nt], 0, 0, 0);
    __builtin_amdgcn_s_setprio(0);
    cur += 1; if (cur >= 3) cur = 0;
  }

  #pragma unroll
  for (int mt = 0; mt < 4; ++mt) {
    #pragma unroll
    for (int nt = 0; nt < 2; ++nt) {
      const int col = n0 + wn + nt * 16 + lr;
      const float bvv = bias[col];
      #pragma unroll
      for (int rr = 0; rr < 4; ++rr) {
        const int row = m0 + wm + mt * 16 + quad * 4 + rr;
        const size_t idx = (size_t)row * N + col;
        float v = acc[mt][nt][rr] + bvv;
        if (mode == 0) {
          ((float*)outp)[idx] = v;
        } else if (mode == 1) {
          ((float*)outp)[idx] = v + res[idx];
        } else if (mode == 2) {
          float gl = 0.5f * v * (1.0f + erff(v * 0.70710678118654752f));
          ((u16*)outp)[idx] = f2bf(gl);
        } else {
          ((u16*)outp)[idx] = f2bf(v);
        }
      }
    }
  }
}

// ---------------------------------------------------------------------------
// logf = log_sigmoid(h @ wf + bf), one wave per row. wfT is (16 x 1024) bf16.
// ---------------------------------------------------------------------------
__global__ __launch_bounds__(64) void logf_kernel(
    const u16* __restrict__ h, const u16* __restrict__ wfT,
    const float* __restrict__ bfv, float* __restrict__ c) {
  const int row = blockIdx.x;
  const int lane = threadIdx.x;
  float acc[16];
  #pragma unroll
  for (int n = 0; n < 16; ++n) acc[n] = 0.f;
  for (int t = 0; t < 16; ++t) {
    int kidx = t * 64 + lane;
    float hv = bf2f(h[(size_t)row * 1024 + kidx]);
    #pragma unroll
    for (int n = 0; n < 16; ++n)
      acc[n] += hv * bf2f(wfT[n * 1024 + kidx]);
  }
  float z = 0.f;
  #pragma unroll
  for (int n = 0; n < 16; ++n) {
    float r = acc[n];
    #pragma unroll
    for (int off = 1; off < 64; off <<= 1) r += __shfl_xor(r, off, 64);
    if (lane == n) z = r;
  }
  if (lane < 16) {
    z += bfv[lane];
    float lf = (z >= 0.f) ? -log1pf(expf(-z)) : (z - log1pf(expf(z)));
    c[(size_t)row * 16 + lane] = lf;
  }
}

__global__ __launch_bounds__(64) void cumsum_kernel(float* __restrict__ c, int S) {
  const int b = blockIdx.x >> 4, h = blockIdx.x & 15;
  const int lane = threadIdx.x;
  float carry = 0.f;
  for (int s0 = 0; s0 < S; s0 += 64) {
    float v = c[(size_t)(b * S + s0 + lane) * 16 + h];
    #pragma unroll
    for (int off = 1; off < 64; off <<= 1) {
      float t = __shfl_up(v, off, 64);
      if (lane >= off) v += t;
    }
    v += carry;
    c[(size_t)(b * S + s0 + lane) * 16 + h] = v;
    carry = __shfl(v, 63, 64);
  }
}

// ---------------------------------------------------------------------------
// V^T prep: qkvb V-part (token-major) -> vtg[(b,h,d), s] bf16
// ---------------------------------------------------------------------------
__global__ __launch_bounds__(256) void vtrans(
    const u16* __restrict__ qkvb, u16* __restrict__ vtg) {
  __shared__ u16 t[32][33];
  const int bh = blockIdx.z, b = bh >> 4, h = bh & 15;
  const int s0 = blockIdx.x * 32, d0 = blockIdx.y * 32;
  const int tx = threadIdx.x & 31, ty = threadIdx.x >> 5;
  for (int i = ty; i < 32; i += 8)
    t[i][tx] = qkvb[(size_t)(b * 2048 + s0 + i) * 3072 + 2048 + h * 64 + d0 + tx];
  __syncthreads();
  for (int i = ty; i < 32; i += 8)
    vtg[(size_t)(bh * 64 + d0 + i) * 2048 + s0 + tx] = t[tx][i];
}

// ---------------------------------------------------------------------------
// Per-tile q/k L2-norm maxima for the fattn tile-skip bound.
// ---------------------------------------------------------------------------
__global__ __launch_bounds__(64) void qk_norms(
    const u16* __restrict__ qkvb, float* __restrict__ qkmax) {
  const int tile = blockIdx.x, bh = blockIdx.y, z = blockIdx.z;
  const int b = bh >> 4, h = bh & 15;
  const int tok = tile * 64 + (int)threadIdx.x;
  const u16* p = qkvb + (size_t)(b * 2048 + tok) * 3072 + z * 1024 + h * 64;
  float s = 0.f;
  #pragma unroll
  for (int i = 0; i < 4; ++i) {
    u32x4 w = *(const u32x4*)(p + i * 16);
    u32x4 w2 = *(const u32x4*)(p + i * 16 + 8);
    #pragma unroll
    for (int e = 0; e < 4; ++e) {
      float lo = __uint_as_float(w[e] << 16);
      float hi = __uint_as_float(w[e] & 0xffff0000u);
      float lo2 = __uint_as_float(w2[e] << 16);
      float hi2 = __uint_as_float(w2[e] & 0xffff0000u);
      s += lo * lo + hi * hi + lo2 * lo2 + hi2 * hi2;
    }
  }
  s = sqrtf(s);
  #pragma unroll
  for (int off = 1; off < 64; off <<= 1) s = fmaxf(s, __shfl_xor(s, off, 64));
  if (threadIdx.x == 0) qkmax[z * 1024 + bh * 32 + tile] = s;
}

// ---------------------------------------------------------------------------
// MFMA flash attention with forget-gate decay bias.
//  - ci dropped (row-constant bias cancels in softmax)
//  - DESCENDING k-tile order + Cauchy-Schwarz early-exit (weights < 2^-40)
//  - 1024 blocks (4/CU), K/V/cj register prefetch pipeline
// ---------------------------------------------------------------------------
#define FS 72
#define NITEMS 1024  // 32 q-tiles * 32 bh
#define L2E 1.4426950408889634f

__global__ __launch_bounds__(256) void fattn(
    const u16* __restrict__ qkvb, const u16* __restrict__ vtg,
    const float* __restrict__ c, const float* __restrict__ qkmax,
    u16* __restrict__ ctx, u32* __restrict__ ctr) {
  __shared__ u16 Qs[64 * FS];
  __shared__ u16 Ks[64 * FS];
  __shared__ u16 Vt[64 * FS];
  __shared__ u16 Ps[64 * FS];
  __shared__ float cjs[64];
  __shared__ float wmn[4];
  __shared__ u32 sh_item;
  const int S = 2048;
  const int tid = threadIdx.x, wave = tid >> 6, lane = tid & 63;
  const int lr = lane & 15, quad = lane >> 4;
  const int w16 = wave * 16;
  const int sr = tid >> 2, scc = (tid & 3) * 16;  // staging row/col

  for (;;) {
    if (tid == 0) sh_item = atomicAdd(ctr, 1u);
    __syncthreads();  // publish item (prev item's LDS reads already fenced)
    const u32 item = sh_item;
    if (item >= NITEMS) return;
    const int qt = 31 - (int)(item >> 5);       // descending work
    const int bh = (int)(item & 31), b = bh >> 4, h = bh & 15;
    const int i0 = qt * 64;

    {  // stage Q tile (64x64 bf16)
      const u16* src = qkvb + (size_t)(b * S + i0 + sr) * 3072 + h * 64 + scc;
      *(u32x4*)&Qs[sr * FS + scc] = *(const u32x4*)src;
      *(u32x4*)&Qs[sr * FS + scc + 8] = *(const u32x4*)(src + 8);
    }
    // prefetch K/V/cj for the DIAGONAL tile (jt = qt) into registers
    u32x4 kr0, kr1, vr0, vr1;
    float cjr = 0.f;
    {
      const u16* ks = qkvb + (size_t)(b * S + i0 + sr) * 3072 + 1024 + h * 64 + scc;
      kr0 = *(const u32x4*)ks;
      kr1 = *(const u32x4*)(ks + 8);
      const u16* vs = vtg + (size_t)(bh * 64 + sr) * 2048 + i0 + scc;
      vr0 = *(const u32x4*)vs;
      vr1 = *(const u32x4*)(vs + 8);
      if (tid < 64) cjr = c[(size_t)(b * S + i0 + tid) * 16 + h];
    }
    // Cauchy-Schwarz score bound scale
    float bscale;
    {
      float qm = qkmax[bh * 32 + qt];
      float km = 0.f;
      for (int t = 0; t <= qt; ++t) km = fmaxf(km, qkmax[1024 + bh * 32 + t]);
      bscale = qm * km * (0.125f * L2E);
    }
    float m_[4], l_[4], alpha[4];
    f32x4 o_[4];
    #pragma unroll
    for (int r = 0; r < 4; ++r) {
      m_[r] = -INFINITY;
      l_[r] = 0.f;
    }
    #pragma unroll
    for (int dt = 0; dt < 4; ++dt) o_[dt] = (f32x4){0.f, 0.f, 0.f, 0.f};

    __syncthreads();  // Q visible
    const bf16x8 aq0 = *(const bf16x8*)&Qs[(w16 + lr) * FS + quad * 8];
    const bf16x8 aq1 = *(const bf16x8*)&Qs[(w16 + lr) * FS + 32 + quad * 8];

    for (int jt = qt; jt >= 0; --jt) {
      const int j0 = jt * 64;
      // write prefetched tile jt to LDS (prev iter's reads fenced by barrier)
      *(u32x4*)&Ks[sr * FS + scc] = kr0;
      *(u32x4*)&Ks[sr * FS + scc + 8] = kr1;
      *(u32x4*)&Vt[sr * FS + scc] = vr0;
      *(u32x4*)&Vt[sr * FS + scc + 8] = vr1;
      if (tid < 64) cjs[tid] = cjr * L2E;
      // issue prefetch for tile jt-1
      if (jt > 0) {
        const int j1 = j0 - 64;
        const u16* ks = qkvb + (size_t)(b * S + j1 + sr) * 3072 + 1024 + h * 64 + scc;
        kr0 = *(const u32x4*)ks;
        kr1 = *(const u32x4*)(ks + 8);
        const u16* vs = vtg + (size_t)(bh * 64 + sr) * 2048 + j1 + scc;
        vr0 = *(const u32x4*)vs;
        vr1 = *(const u32x4*)(vs + 8);
        if (tid < 64) cjr = c[(size_t)(b * S + j1 + tid) * 16 + h];
      }
      __syncthreads();  // K/V visible

      f32x4 sc[4];
      #pragma unroll
      for (int nt = 0; nt < 4; ++nt) {
        bf16x8 bk0 = *(const bf16x8*)&Ks[(nt * 16 + lr) * FS + quad * 8];
        bf16x8 bk1 = *(const bf16x8*)&Ks[(nt * 16 + lr) * FS + 32 + quad * 8];
        f32x4 z = {0.f, 0.f, 0.f, 0.f};
        z = __builtin_amdgcn_mfma_f32_16x16x32_bf16(aq0, bk0, z, 0, 0, 0);
        z = __builtin_amdgcn_mfma_f32_16x16x32_bf16(aq1, bk1, z, 0, 0, 0);
        sc[nt] = z;
      }
      const bool diag = (jt == qt);
      #pragma unroll
      for (int r = 0; r < 4; ++r) {
        const int i = i0 + w16 + quad * 4 + r;
        float lg[4], mrow = -INFINITY;
        #pragma unroll
        for (int nt = 0; nt < 4; ++nt) {
          const int j = j0 + nt * 16 + lr;
          float v = sc[nt][r] * (0.125f * L2E) - cjs[nt * 16 + lr];
          if (diag && (j > i)) v = -INFINITY;
          lg[nt] = v;
          mrow = fmaxf(mrow, v);
        }
        #pragma unroll
        for (int off = 1; off < 16; off <<= 1)
          mrow = fmaxf(mrow, __shfl_xor(mrow, off, 64));
        const float mn = fmaxf(m_[r], mrow);
        alpha[r] = __builtin_exp2f(m_[r] - mn);
        m_[r] = mn;
        float rs = 0.f;
        #pragma unroll
        for (int nt = 0; nt < 4; ++nt) {
          const float p = __builtin_exp2f(lg[nt] - mn);
          Ps[(w16 + quad * 4 + r) * FS + nt * 16 + lr] = f2bf(p);
          rs += p;
        }
        l_[r] = l_[r] * alpha[r] + rs;  // per-lane partial (reduced at end)
      }
      // make this wave's P writes visible to its own b128 reads
      asm volatile("s_waitcnt lgkmcnt(0)" ::: "memory");
      #pragma unroll
      for (int dt = 0; dt < 4; ++dt)
        #pragma unroll
        for (int r = 0; r < 4; ++r) o_[dt][r] *= alpha[r];
      bf16x8 ap0 = *(const bf16x8*)&Ps[(w16 + lr) * FS + quad * 8];
      bf16x8 ap1 = *(const bf16x8*)&Ps[(w16 + lr) * FS + 32 + quad * 8];
      #pragma unroll
      for (int dt = 0; dt < 4; ++dt) {
        bf16x8 bv0 = *(const bf16x8*)&Vt[(dt * 16 + lr) * FS + quad * 8];
        bf16x8 bv1 = *(const bf16x8*)&Vt[(dt * 16 + lr) * FS + 32 + quad * 8];
        o_[dt] = __builtin_amdgcn_mfma_f32_16x16x32_bf16(ap0, bv0, o_[dt], 0, 0, 0);
        o_[dt] = __builtin_amdgcn_mfma_f32_16x16x32_bf16(ap1, bv1, o_[dt], 0, 0, 0);
      }
      // publish this wave's running-max minimum for the skip decision
      {
        float wmin = fminf(fminf(m_[0], m_[1]), fminf(m_[2], m_[3]));
        wmin = fminf(wmin, __shfl_xor(wmin, 16, 64));
        wmin = fminf(wmin, __shfl_xor(wmin, 32, 64));
        if (lane == 0) wmn[wave] = wmin;
      }
      __syncthreads();  // all reads of Ks/Vt done before next iter's writes
      if (jt > 0) {
        const float bmin = fminf(fminf(wmn[0], wmn[1]), fminf(wmn[2], wmn[3]));
        const float cend = c[(size_t)(b * S + j0 - 1) * 16 + h];
        if (bscale - cend * L2E < bmin - 40.f) break;
      }
    }
    #pragma unroll
    for (int r = 0; r < 4; ++r) {
      float lt = l_[r];
      #pragma unroll
      for (int off = 1; off < 16; off <<= 1) lt += __shfl_xor(lt, off, 64);
      const float inv = 1.0f / lt;
      const size_t base = (size_t)(b * S + i0 + w16 + quad * 4 + r) * 1024 + h * 64;
      #pragma unroll
      for (int dt = 0; dt < 4; ++dt)
        ctx[base + dt * 16 + lr] = f2bf(o_[dt][r] * inv);
    }
  }
}

// ---------------------------------------------------------------------------
extern "C" void kernel_launch(void* const* d_in, const int* in_sizes, int n_in,
                              void* d_out, int out_size, void* d_ws, size_t ws_size,
                              hipStream_t stream) {
  const float* x    = (const float*)d_in[0];
  const float* ln1g = (const float*)d_in[1];
  const float* ln1b = (const float*)d_in[2];
  const float* wq   = (const float*)d_in[3];
  const float* bq   = (const float*)d_in[4];
  const float* wk   = (const float*)d_in[5];
  const float* bk   = (const float*)d_in[6];
  const float* wv   = (const float*)d_in[7];
  const float* bv   = (const float*)d_in[8];
  const float* wo   = (const float*)d_in[9];
  const float* bo   = (const float*)d_in[10];
  const float* wf   = (const float*)d_in[11];
  const float* bfv  = (const float*)d_in[12];
  const float* ln2g = (const float*)d_in[13];
  const float* ln2b = (const float*)d_in[14];
  const float* w1   = (const float*)d_in[15];
  const float* b1   = (const float*)d_in[16];
  const float* w2   = (const float*)d_in[17];
  const float* b2   = (const float*)d_in[18];
  float* out = (float*)d_out;

  char* ws = (char*)d_ws;
  const size_t MB = 1024 * 1024;
  u16*   wqkvT = (u16*)(ws + 0 * MB);        // 3072x1024 bf16 (6 MB)
  u16*   woT   = (u16*)(ws + 6 * MB);        // 1024x1024 bf16
  u16*   w1T   = (u16*)(ws + 8 * MB);        // 4096x1024 bf16
  u16*   w2T   = (u16*)(ws + 16 * MB);       // 1024x4096 bf16
  u16*   wfT   = (u16*)(ws + 24 * MB);       // 16x1024 bf16
  float* bqkv  = (float*)(ws + 24 * MB + 65536);  // 3072 fp32
  u32*   fctr  = (u32*)(ws + 24 * MB + 131072);   // work-steal counter
  u16*   hbuf  = (u16*)(ws + 25 * MB);       // 4096x1024 bf16
  u16*   ctx   = (u16*)(ws + 33 * MB);       // 4096x1024 bf16
  u16*   qkvb  = (u16*)(ws + 41 * MB);       // 4096x3072 bf16 (24 MB)
  u16*   vtg   = (u16*)(ws + 65 * MB);       // (32*64)x2048 bf16 (8 MB)
  float* cb    = (float*)(ws + 73 * MB);     // 4096x16 fp32 (256 KB)
  float* qkmax = (float*)(ws + 73 * MB + 262144);  // 2x32x32 fp32 (8 KB)
  u16*   act1  = (u16*)(ws + 74 * MB);       // 4096x4096 bf16 (32 MB)

  dim3 blk(256);
  // weight prep (pack3 also zeroes the fattn work-steal counter, on-stream)
  transpose_cast4<<<dim3(32, 32, 4), blk, 0, stream>>>(wq, wk, wv, wo,
                                                       wqkvT, woT);
  transpose_cast<<<dim3(128, 32), blk, 0, stream>>>(w1, w1T, 1024, 4096);
  transpose_cast<<<dim3(32, 128), blk, 0, stream>>>(w2, w2T, 4096, 1024);
  transpose_cast<<<dim3(1, 32), blk, 0, stream>>>(wf, wfT, 1024, 16);
  pack3<<<12, blk, 0, stream>>>(bq, bk, bv, bqkv, fctr);
  // LN1
  ln_kernel<<<4096, blk, 0, stream>>>(x, ln1g, ln1b, hbuf, nullptr, nullptr);
  // fused QKV projection -> bf16 (4096 x 3072), 768 blocks = 3/CU
  gemm_bt<<<dim3(24, 32), blk, 0, stream>>>(hbuf, wqkvT, bqkv, nullptr, qkvb,
                                            4096, 3072, 1024, 3);
  // forget gate
  logf_kernel<<<4096, dim3(64), 0, stream>>>(hbuf, wfT, bfv, cb);
  cumsum_kernel<<<32, dim3(64), 0, stream>>>(cb, 2048);
  // V^T prep + per-tile q/k norm maxima + attention (work-stealing)
  vtrans<<<dim3(64, 2, 32), blk, 0, stream>>>(qkvb, vtg);
  qk_norms<<<dim3(32, 32, 2), dim3(64), 0, stream>>>(qkvb, qkmax);
  fattn<<<dim3(1024), blk, 0, stream>>>(qkvb, vtg, cb, qkmax, ctx, fctr);
  // out projection + residual -> d_out
  gemm_n64<<<dim3(16, 32), blk, 0, stream>>>(ctx, woT, bo, x, out,
                                             4096, 1024, 1024, 1);
  // LN2 (fused: also seeds out += b2 for MLP2's atomic split-K accumulate)
  ln_kernel<<<4096, blk, 0, stream>>>(out, ln2g, ln2b, hbuf, out, b2);
  // MLP1: 1024 blocks
  gemm_bt<<<dim3(32, 32), blk, 0, stream>>>(hbuf, w1T, b1, nullptr, act1,
                                            4096, 4096, 1024, 2);
  // MLP2: split-K x2 with 128^2 tile, 3-buffer pipeline, atomic accumulate
  gemm_bt_sk<<<dim3(8, 32, 2), blk, 0, stream>>>(act1, w2T, out,
                                                 4096, 1024, 4096, 2048);
}